// Round 1
// baseline (1580.378 us; speedup 1.0000x reference)
//
#include <hip/hip_runtime.h>

// y[b,co,h,w] = sum_ci x[b,ci,h,w] * W[ci,co] + bias[co] at active voxels
// (any channel != 0), else 0.  B=8, CIN=32, COUT=64, H=W=512.
// Memory-bound: 256 MiB read + 512 MiB write -> ~128 us floor at 6.3 TB/s.
//
// Round 1 restructure: accumulator-resident blocking, 1 position/thread.
//  - acc[64] lives in VGPRs (cannot be rematerialized), each x channel is
//    loaded exactly once -> single-pass HBM reads (prev kernel: compiler
//    sank the 128-reg x cache into the cout loop -> 2.37x read over-fetch).
//  - W/bias read with wave-uniform indices -> scalarized to s_load + SGPR
//    FMA operands; no LDS, no __syncthreads.
//  - ~110 VGPRs under __launch_bounds__(256,4) -> 4 waves/SIMD (vs 22% occ).
//  - 2048 straight-line FMAs (~22 KB) fits the 32 KB I$ (prev: ~70 KB).
//  - nontemporal stores: output is write-once streaming.

#define HW_SHIFT 18          // H*W = 512*512 = 2^18
#define HW_ (1 << HW_SHIFT)
#define CIN 32
#define COUT 64

__global__ __launch_bounds__(256, 4) void spconv1x1_kernel(
    const float* __restrict__ x, const float* __restrict__ Wm,
    const float* __restrict__ bias, float* __restrict__ out)
{
    const long p   = (long)blockIdx.x * 256 + threadIdx.x;  // one position
    const int bidx = (int)(p >> HW_SHIFT);                  // batch index
    const int sp   = (int)(p & (HW_ - 1));                  // pos within H*W

    const float* xb = x + (((long)bidx * CIN) << HW_SHIFT) + sp;

    // All 32 input channels for this position: 32 independent coalesced
    // dword loads (256 B/wave each), issued back-to-back for MLP.
    float xv[CIN];
#pragma unroll
    for (int ci = 0; ci < CIN; ci++)
        xv[ci] = xb[(long)ci << HW_SHIFT];

    // Active mask: any channel != 0 (exact reference semantics, handles -0.0).
    int act = 0;
#pragma unroll
    for (int ci = 0; ci < CIN; ci++)
        act |= (xv[ci] != 0.0f);

    float acc[COUT];
#pragma unroll
    for (int co = 0; co < COUT; co++) acc[co] = 0.0f;

    // acc[co] += xv[ci] * W[ci][co]; W index is wave-uniform -> s_load,
    // FMA takes the weight as an SGPR operand (1 SGPR/VALU instr: legal).
    // Same summation order (ci ascending, fma chain) as the passing kernel.
#pragma unroll
    for (int ci = 0; ci < CIN; ci++) {
        const float xi = xv[ci];
        const float4* wrow = (const float4*)(Wm + ci * COUT);
#pragma unroll
        for (int co4 = 0; co4 < COUT / 4; co4++) {
            const float4 w = wrow[co4];
            acc[co4 * 4 + 0] = fmaf(xi, w.x, acc[co4 * 4 + 0]);
            acc[co4 * 4 + 1] = fmaf(xi, w.y, acc[co4 * 4 + 1]);
            acc[co4 * 4 + 2] = fmaf(xi, w.z, acc[co4 * 4 + 2]);
            acc[co4 * 4 + 3] = fmaf(xi, w.w, acc[co4 * 4 + 3]);
        }
    }

    float* ob = out + (((long)bidx * COUT) << HW_SHIFT) + sp;
#pragma unroll
    for (int co = 0; co < COUT; co++) {
        const float r = act ? acc[co] + bias[co] : 0.0f;  // bias -> s_load
        __builtin_nontemporal_store(r, ob + ((long)co << HW_SHIFT));
    }
}

extern "C" void kernel_launch(void* const* d_in, const int* in_sizes, int n_in,
                              void* d_out, int out_size, void* d_ws, size_t ws_size,
                              hipStream_t stream) {
    const float* x  = (const float*)d_in[0];   // [B, CIN, H, W] fp32
    const float* Wm = (const float*)d_in[1];   // [CIN, COUT] fp32
    const float* b  = (const float*)d_in[2];   // [COUT] fp32
    float* out = (float*)d_out;                // [B, COUT, H, W] fp32

    const long npos   = (long)in_sizes[0] / CIN;  // B*H*W = 2,097,152
    const int  blocks = (int)(npos / 256);        // 8192

    spconv1x1_kernel<<<blocks, 256, 0, stream>>>(x, Wm, b, out);
}

// Round 2
// 743.615 us; speedup vs baseline: 2.1253x; 2.1253x over previous
//
#include <hip/hip_runtime.h>

// y[b,co,h,w] = sum_ci x[b,ci,h,w] * W[ci,co] + bias[co] at active voxels
// (any channel != 0), else 0.  B=8, CIN=32, COUT=64, H=W=512.
// Memory-bound: 256 MiB read + 512 MiB write -> ~128 us floor at 6.3 TB/s.
//
// Round 2: cout-split structure.
//  - Round 0 (446us/dispatch): float4 accesses, but 128-reg x cache forced
//    remat -> 2.37x read over-fetch.  Round 1 (1104us): 96 simultaneously-
//    live floats broke the allocator (VGPR_Count=32, 17x VALU inflation).
//  - Now: thread = 4 positions x 16 couts (quarter of COUT).  acc = 64 VGPR
//    (long-lived, un-rematerializable), x loaded in 8-channel chunks inside
//    a ROLLED 4-iteration loop (32 VGPR, dies per iteration).  Peak live-set
//    ~108 < 128 cap from __launch_bounds__(256,4).
//  - 4 waves of a block = 4 cout-quarters of the SAME 256 positions: x
//    re-reads hit L2 (3x extra L2 traffic ~ 25us aggregate, HBM fetch 1x).
//  - W/bias via readfirstlane(cg) -> provably uniform -> s_load, no LDS.

#define HW_SHIFT 18          // H*W = 512*512 = 2^18
#define HW_ (1 << HW_SHIFT)
#define CIN 32
#define COUT 64
#define CB 16                // couts per thread (COUT/4)
#define KC 8                 // input-channel chunk

__global__ __launch_bounds__(256, 4) void spconv1x1_kernel(
    const float* __restrict__ x, const float* __restrict__ Wm,
    const float* __restrict__ bias, float* __restrict__ out)
{
    const int l  = threadIdx.x & 63;                       // lane
    const int cg = __builtin_amdgcn_readfirstlane(threadIdx.x >> 6); // 0..3
    const long q  = (long)blockIdx.x * 64 + l;             // quad index
    const long p0 = q * 4;                                 // first position
    const int bidx = (int)(p0 >> HW_SHIFT);                // batch
    const int sp   = (int)(p0 & (HW_ - 1));                // pos within H*W
    // Quads never straddle a batch (HW divisible by 4).

    const float* xb = x + (((long)bidx * CIN) << HW_SHIFT) + sp;

    float4 acc[CB];
#pragma unroll
    for (int i = 0; i < CB; i++) acc[i] = make_float4(0.f, 0.f, 0.f, 0.f);
    int a0 = 0, a1 = 0, a2 = 0, a3 = 0;

    // Rolled chunk loop: 8 float4 x-loads in flight per iteration, consumed
    // against 16 couts.  Live-set stays ~108 VGPR; acc cannot be remat'd.
#pragma unroll 1
    for (int c0 = 0; c0 < CIN; c0 += KC) {
        float4 xv[KC];
#pragma unroll
        for (int k = 0; k < KC; k++)
            xv[k] = *(const float4*)(xb + ((long)(c0 + k) << HW_SHIFT));

#pragma unroll
        for (int k = 0; k < KC; k++) {
            a0 |= (xv[k].x != 0.0f);
            a1 |= (xv[k].y != 0.0f);
            a2 |= (xv[k].z != 0.0f);
            a3 |= (xv[k].w != 0.0f);
            // W row slice for our cout quarter: uniform address -> s_load.
            const float* wr = Wm + (c0 + k) * COUT + cg * CB;
#pragma unroll
            for (int i4 = 0; i4 < CB / 4; i4++) {
                const float4 w = *(const float4*)(wr + i4 * 4);
                acc[i4 * 4 + 0].x = fmaf(xv[k].x, w.x, acc[i4 * 4 + 0].x);
                acc[i4 * 4 + 0].y = fmaf(xv[k].y, w.x, acc[i4 * 4 + 0].y);
                acc[i4 * 4 + 0].z = fmaf(xv[k].z, w.x, acc[i4 * 4 + 0].z);
                acc[i4 * 4 + 0].w = fmaf(xv[k].w, w.x, acc[i4 * 4 + 0].w);
                acc[i4 * 4 + 1].x = fmaf(xv[k].x, w.y, acc[i4 * 4 + 1].x);
                acc[i4 * 4 + 1].y = fmaf(xv[k].y, w.y, acc[i4 * 4 + 1].y);
                acc[i4 * 4 + 1].z = fmaf(xv[k].z, w.y, acc[i4 * 4 + 1].z);
                acc[i4 * 4 + 1].w = fmaf(xv[k].w, w.y, acc[i4 * 4 + 1].w);
                acc[i4 * 4 + 2].x = fmaf(xv[k].x, w.z, acc[i4 * 4 + 2].x);
                acc[i4 * 4 + 2].y = fmaf(xv[k].y, w.z, acc[i4 * 4 + 2].y);
                acc[i4 * 4 + 2].z = fmaf(xv[k].z, w.z, acc[i4 * 4 + 2].z);
                acc[i4 * 4 + 2].w = fmaf(xv[k].w, w.z, acc[i4 * 4 + 2].w);
                acc[i4 * 4 + 3].x = fmaf(xv[k].x, w.w, acc[i4 * 4 + 3].x);
                acc[i4 * 4 + 3].y = fmaf(xv[k].y, w.w, acc[i4 * 4 + 3].y);
                acc[i4 * 4 + 3].z = fmaf(xv[k].z, w.w, acc[i4 * 4 + 3].z);
                acc[i4 * 4 + 3].w = fmaf(xv[k].w, w.w, acc[i4 * 4 + 3].w);
            }
        }
    }

    float* ob = out + (((long)bidx * COUT) << HW_SHIFT) + sp;

#pragma unroll
    for (int i4 = 0; i4 < CB / 4; i4++) {
        const float4 bb = *(const float4*)(bias + cg * CB + i4 * 4);  // s_load
#pragma unroll
        for (int j = 0; j < 4; j++) {
            const int i  = i4 * 4 + j;
            const float bj = (j == 0) ? bb.x : (j == 1) ? bb.y
                           : (j == 2) ? bb.z : bb.w;
            float4 r;
            r.x = a0 ? acc[i].x + bj : 0.f;
            r.y = a1 ? acc[i].y + bj : 0.f;
            r.z = a2 ? acc[i].z + bj : 0.f;
            r.w = a3 ? acc[i].w + bj : 0.f;
            *(float4*)(ob + ((long)(cg * CB + i) << HW_SHIFT)) = r;
        }
    }
}

extern "C" void kernel_launch(void* const* d_in, const int* in_sizes, int n_in,
                              void* d_out, int out_size, void* d_ws, size_t ws_size,
                              hipStream_t stream) {
    const float* x  = (const float*)d_in[0];   // [B, CIN, H, W] fp32
    const float* Wm = (const float*)d_in[1];   // [CIN, COUT] fp32
    const float* b  = (const float*)d_in[2];   // [COUT] fp32
    float* out = (float*)d_out;                // [B, COUT, H, W] fp32

    const long npos  = (long)in_sizes[0] / CIN;   // B*H*W = 2,097,152
    const long quads = npos / 4;                  // 524,288
    const int  blocks = (int)(quads / 64);        // 8192 (64 quads/block)

    spconv1x1_kernel<<<blocks, 256, 0, stream>>>(x, Wm, b, out);
}